// Round 11
// baseline (472.200 us; speedup 1.0000x reference)
//
#include <hip/hip_runtime.h>
#include <stdint.h>

#define D_DIM 256
#define BI 32        // i-rows per block (4 blocks/CU -> 32 waves/CU, the cap)
#define TJ 128       // j-tile
#define CHUNK 4096   // j per block (grid = 256 x 4 = 1024 blocks = 4/CU)

typedef unsigned short ushort_t;
typedef __attribute__((ext_vector_type(8))) short bf16x8;   // 8 bf16 = 4 VGPRs
typedef __attribute__((ext_vector_type(4))) float f32x4;

__device__ __forceinline__ unsigned short f2bf(float f) {
  union { float f; unsigned u; } x; x.f = f;
  unsigned r = x.u + 0x7FFFu + ((x.u >> 16) & 1u);  // round-nearest-even
  return (unsigned short)(r >> 16);
}

__device__ __forceinline__ float fast_sqrt(float x) {
#if __has_builtin(__builtin_amdgcn_sqrtf)
  return __builtin_amdgcn_sqrtf(x);
#else
  return sqrtf(x);
#endif
}
__device__ __forceinline__ float fast_exp2(float x) {
#if __has_builtin(__builtin_amdgcn_exp2f)
  return __builtin_amdgcn_exp2f(x);
#else
  return exp2f(x);
#endif
}

// async global->LDS, 16B per lane. LDS dest = wave-uniform base + lane*16.
__device__ __forceinline__ void g2l16(const void* g, void* l) {
  __builtin_amdgcn_global_load_lds(
      (__attribute__((address_space(1))) void*)(uintptr_t)g,
      (__attribute__((address_space(3))) void*)(unsigned)(uintptr_t)l,
      16, 0, 0);
}

// ---------------- prep (fused): cast + norms + Tb + TbF + TTF in ONE pass ----------------
// r9-verified: 512 blocks x 256 threads, 32 rows/block (2 blocks/CU).
__global__ __launch_bounds__(256) void
prep_all(const float* __restrict__ G, const float* __restrict__ P,
         ushort_t* __restrict__ Tb, ushort_t* __restrict__ TbF,
         ushort_t* __restrict__ TTF, float* __restrict__ nrm,
         int Bn, int Ttot)
{
  __shared__ ushort_t Ls[32][264];   // pad 8: row stride 528B (16B-aligned)
  const int b = blockIdx.x, t = threadIdx.x;
  const int w = t >> 6, lane = t & 63;
  const int r0 = b * 32;
  const int jsteps = Ttot >> 5;

  #pragma unroll
  for (int it = 0; it < 8; it++) {
    const int rl = it * 4 + w;                // row within block (wave w owns it)
    const int r = r0 + rl;
    const float* src = (r < Bn) ? (G + (size_t)r * D_DIM)
                                : (P + (size_t)(r - Bn) * D_DIM);
    float4 v = *(const float4*)(src + lane * 4);
    ushort4 u;
    u.x = f2bf(v.x); u.y = f2bf(v.y); u.z = f2bf(v.z); u.w = f2bf(v.w);
    *(ushort4*)&Tb[(size_t)r * D_DIM + lane * 4] = u;
    *(ushort4*)&Ls[rl][lane * 4] = u;
    float s = v.x * v.x + v.y * v.y + v.z * v.z + v.w * v.w;
    #pragma unroll
    for (int o = 32; o > 0; o >>= 1) s += __shfl_down(s, o, 64);
    if (lane == 0) nrm[r] = s;                // plain store: row is wave-local
  }
  __syncthreads();

  // TbF: A-fragment layout, 2 row-groups of 16
  #pragma unroll
  for (int ii = 0; ii < 4; ii++) {
    const int flat8 = ii * 2048 + t * 8;      // [0, 8192)
    const int g4 = flat8 >> 12;               // row-group 0..1
    const int fl = flat8 & 4095;
    const int ks = fl >> 9;
    const int e = fl & 511;
    const int q = (e >> 7) & 3, m = (e >> 3) & 15;
    uint4 val = *(const uint4*)&Ls[g4 * 16 + m][ks * 32 + q * 8];
    *(uint4*)&TbF[(size_t)(b * 2 + g4) * 4096 + fl] = val;
  }

  // TTF: transposed fragment layout; this block = jstep b exactly
  #pragma unroll
  for (int ii = 0; ii < 4; ii++) {
    const int flat8 = ii * 2048 + t * 8;      // [0, 8192)
    const int dgrp = flat8 >> 9;              // 0..15
    const int e = flat8 & 511;
    const int dd = dgrp >> 2, dsub = dgrp & 3;
    const int q = (e >> 7) & 3, m = (e >> 3) & 15;
    const int col = dd * 64 + dsub * 16 + m;
    const int jrow = q * 8;
    ushort_t vals[8];
    #pragma unroll
    for (int idx = 0; idx < 8; idx++) vals[idx] = Ls[jrow + idx][col];
    *(uint4*)&TTF[((size_t)dgrp * jsteps + b) * 512 + e] = *(uint4*)vals;
  }
}

// ---------------- fused: S^T -> kv (LDS dbuf) -> O^T, 1 barrier/tile ----------------
// Round-19: r4/r9 schedule with BI 64 -> 32, i.e. HALF the block, DOUBLE the
// blocks (1024 = 4/CU, 32 waves/CU = hw cap). The r4 structure is
// latency-chain-bound at 4 waves/SIMD (MfmaUtil 39%, both pipes <45%, r2/r5/r6
// showed barrier-domains / issue-order / LDS-byte swaps are all non-levers);
// this doubles TLP while keeping every layout & swizzle formula identical
// (row counts halve; index algebra verbatim). LDS 32 KB/block; VGPR budget
// forced to 64 via __launch_bounds__(512,8) -- accumulators halved vs r9's
// 60-VGPR fit, so no spill expected.
//   GEMM1 wave grid: 4(j32) x 2(i16), acc1[2].
//   GEMM2 wave grid: 8(d32) x 1(i32), accO[2][2].
__global__ __launch_bounds__(512, 8) void
fused_kernel(const ushort_t* __restrict__ Tb, const ushort_t* __restrict__ TbF,
             const ushort_t* __restrict__ TTF, const float* __restrict__ nrm,
             float* __restrict__ sg, float* __restrict__ sp,
             float* __restrict__ Part, int Bn, int Ttot)
{
  __shared__ ushort_t Gsm[4 * 2048];      // 16 KB resident i-tile: [kq][row32][64 ^ swz]
  __shared__ ushort_t Ksm[2][32 * 128];   // 2 x 8 KB kv: [i32][128j ^ swz]

  const int t = threadIdx.x;
  const int w = t >> 6, lane = t & 63;
  const int q = lane >> 4, c = lane & 15;
  const int wj = w >> 1, wcol = w & 1;    // GEMM1 4x2 wave grid (32j x 16i each)
  const int wd = w;                       // GEMM2 8x1 wave grid (32d x 32i each)

  // XCD-chunk swizzle (bijective): XCD pair k <- chunk k>>1; i-blocks interleave.
  const int bid = blockIdx.y * gridDim.x + blockIdx.x;    // 0..1023
  const int by = (bid & 7) >> 1;                  // chunk index 0..3
  const int bx = ((bid >> 3) << 1) | (bid & 1);   // i-block 0..255
  const int i0 = bx * BI;
  const int chunk0 = by * CHUNK;
  const bool gen = (chunk0 < Bn);
  const int swz = (c & 7) * 8;            // per-lane constant XOR
  const int jsteps = Ttot >> 5;
  const size_t mstride = (size_t)jsteps * 512;

  // ---- stage resident G tile (32 rows x 256 k, swizzled): 2 rounds x 2 kq ----
  const int srow = (t >> 3) & 31;                        // 0..31
  const int scol = ((t & 7) * 8) ^ ((srow & 7) * 8);     // source col within 64
  {
    const ushort_t* gsrc = Tb + (size_t)(i0 + srow) * D_DIM;
    #pragma unroll
    for (int r = 0; r < 2; r++) {
      const int kq = r * 2 + (t >> 8);                   // wave-uniform
      g2l16(gsrc + kq * 64 + scol, Gsm + kq * 2048 + (t & 255) * 8);
    }
  }

  f32x4 accO[2][2];
  #pragma unroll
  for (int m = 0; m < 2; m++)
    #pragma unroll
    for (int n = 0; n < 2; n++) accO[m][n] = (f32x4)0.f;
  float rs = 0.f;
  const float ni = nrm[i0 + wcol * 16 + c];
  const int ig_glob = i0 + wcol * 16 + c;

  // persistent GEMM1 af prefetch registers (ks=0 of current tile)
  bf16x8 af0c, af1c;
  {
    const ushort_t* ap = TbF + ((size_t)((chunk0 >> 4) + wj * 2) * 8) * 512 + lane * 8;
    af0c = *(const bf16x8*)ap;
    af1c = *(const bf16x8*)(ap + 4096);
  }

  __syncthreads();   // Gsm ready

  for (int jt = 0; jt < CHUNK; jt += TJ) {
    const int j0g = chunk0 + jt;
    ushort_t* Kbuf = Ksm[(jt >> 7) & 1];
    const ushort_t* afp = TbF + ((size_t)((j0g >> 4) + wj * 2) * 8) * 512 + lane * 8;

    // prefetch nrm[j] for this tile's epilogue (hidden under GEMM1)
    float4 njv[2];
    #pragma unroll
    for (int mt = 0; mt < 2; mt++)
      njv[mt] = *(const float4*)&nrm[j0g + wj * 32 + mt * 16 + q * 4];

    // ---- GEMM1: S^T[j32 x i16] per wave, K=256; af global (dbuf), bf from Gsm ----
    f32x4 acc1[2];
    #pragma unroll
    for (int m = 0; m < 2; m++) acc1[m] = (f32x4)0.f;

    #pragma unroll
    for (int ks = 0; ks < 8; ks++) {
      bf16x8 afn0, afn1;
      if (ks < 7) {
        afn0 = *(const bf16x8*)(afp + (ks + 1) * 512);
        afn1 = *(const bf16x8*)(afp + 4096 + (ks + 1) * 512);
      }
      bf16x8 bfv = *(const bf16x8*)&Gsm[(ks >> 1) * 2048 + (wcol * 16 + c) * 64 + ((((ks & 1) * 32) + q * 8) ^ swz)];
      acc1[0] = __builtin_amdgcn_mfma_f32_16x16x32_bf16(af0c, bfv, acc1[0], 0, 0, 0);
      acc1[1] = __builtin_amdgcn_mfma_f32_16x16x32_bf16(af1c, bfv, acc1[1], 0, 0, 0);
      if (ks < 7) { af0c = afn0; af1c = afn1; }
    }

    // ---- epilogue: kv = exp(-dist/20), rowsum, pack -> Kbuf ----
    #pragma unroll
    for (int mt = 0; mt < 2; mt++) {
      const int jl = wj * 32 + mt * 16 + q * 4;   // local j of reg 0
      const int jb = j0g + jl;                    // global j
      const float nj[4] = {njv[mt].x, njv[mt].y, njv[mt].z, njv[mt].w};
      const int il = wcol * 16 + c;
      uint32_t pb[4];
      #pragma unroll
      for (int reg = 0; reg < 4; reg++) {
        float sq = fmaxf(ni + nj[reg] - 2.f * acc1[mt][reg], 0.f);
        float dd = fast_sqrt(sq);
        float kv = fast_exp2(dd * -0.07213475204444817f);  // exp(-dd/20)
        if (gen && (jb + reg == ig_glob)) kv = 0.f;
        rs += kv;
        union { float f; uint32_t u; } uu; uu.f = kv; pb[reg] = uu.u;
      }
      uint2 pk;  // truncating bf16 pack
      pk.x = __builtin_amdgcn_perm(pb[1], pb[0], 0x07060302u);
      pk.y = __builtin_amdgcn_perm(pb[3], pb[2], 0x07060302u);
      *(uint2*)&Kbuf[il * 128 + (jl ^ swz)] = pk;
    }

    // pre-barrier prefetches: completed by the barrier's vmcnt(0) drain,
    // issued under the epilogue VALU work above.
    const ushort_t* a2p = TTF + ((size_t)(wd * 2) * jsteps + (j0g >> 5)) * 512 + lane * 8;
    bf16x8 a20 = *(const bf16x8*)a2p;
    bf16x8 a21 = *(const bf16x8*)(a2p + mstride);
    {
      const int jn = (jt + TJ < CHUNK) ? (j0g + TJ) : chunk0;
      const ushort_t* ap = TbF + ((size_t)((jn >> 4) + wj * 2) * 8) * 512 + lane * 8;
      af0c = *(const bf16x8*)ap;
      af1c = *(const bf16x8*)(ap + 4096);
    }

    __syncthreads();   // Kbuf ready (sole barrier; dbuf covers cross-tile reuse)

    // ---- GEMM2: O^T[d32 x i32] per wave, K=128; a2 global (dbuf), kf from Kbuf ----
    #pragma unroll
    for (int ks = 0; ks < 4; ks++) {
      bf16x8 a2n0, a2n1;
      if (ks < 3) {
        a2n0 = *(const bf16x8*)(a2p + (ks + 1) * 512);
        a2n1 = *(const bf16x8*)(a2p + mstride + (ks + 1) * 512);
      }
      bf16x8 kf[2];
      #pragma unroll
      for (int nt = 0; nt < 2; nt++)
        kf[nt] = *(const bf16x8*)&Kbuf[(nt * 16 + c) * 128 + ((ks * 32 + q * 8) ^ swz)];
      #pragma unroll
      for (int nt = 0; nt < 2; nt++) {
        accO[0][nt] = __builtin_amdgcn_mfma_f32_16x16x32_bf16(a20, kf[nt], accO[0][nt], 0, 0, 0);
        accO[1][nt] = __builtin_amdgcn_mfma_f32_16x16x32_bf16(a21, kf[nt], accO[1][nt], 0, 0, 0);
      }
      if (ks < 3) { a20 = a2n0; a21 = a2n1; }
    }
    // no barrier: next tile writes the other Ksm buffer
  }

  // rowsum partials -> sg/sp
  float* S = gen ? sg : sp;
  {
    float r = rs;
    r += __shfl_xor(r, 16, 64);
    r += __shfl_xor(r, 32, 64);
    if (lane < 16) atomicAdd(&S[i0 + wcol * 16 + lane], r);
  }
  // O^T partials -> Part[chunk][i][d] (f32x4, 16B aligned)
  float* Pdst = Part + (size_t)by * ((size_t)8192 * D_DIM);
  #pragma unroll
  for (int mt = 0; mt < 2; mt++)
    #pragma unroll
    for (int nt = 0; nt < 2; nt++) {
      const int d = wd * 32 + mt * 16 + q * 4;
      const int ig = i0 + nt * 16 + c;
      *(f32x4*)&Pdst[(size_t)ig * D_DIM + d] = accO[mt][nt];
    }
}

// ---------------- combine: out = sg*sum(pos parts) - sp*sum(gen parts) ----------------
__global__ __launch_bounds__(256) void
combine_kernel(float* __restrict__ out, const float* __restrict__ Part,
               const float* __restrict__ sg, const float* __restrict__ sp)
{
  const size_t idx = (size_t)blockIdx.x * 256 + threadIdx.x;   // f32x4 index
  const size_t qstride = (size_t)8192 * (D_DIM / 4);
  const int i = (int)(idx >> 6);
  const f32x4* p = (const f32x4*)Part;
  f32x4 g0 = p[idx], g1 = p[idx + qstride];
  f32x4 p0 = p[idx + 2 * qstride], p1 = p[idx + 3 * qstride];
  const float sgv = sg[i], spv = sp[i];
  f32x4 r;
  #pragma unroll
  for (int k = 0; k < 4; k++) r[k] = sgv * (p0[k] + p1[k]) - spv * (g0[k] + g1[k]);
  ((f32x4*)out)[idx] = r;
}

extern "C" void kernel_launch(void* const* d_in, const int* in_sizes, int n_in,
                              void* d_out, int out_size, void* d_ws, size_t ws_size,
                              hipStream_t stream)
{
  const float* G = (const float*)d_in[0];
  const float* P = (const float*)d_in[1];
  const int Bn = in_sizes[0] / D_DIM;   // 8192
  const int Xn = in_sizes[1] / D_DIM;   // 8192
  const int Ttot = Bn + Xn;             // 16384

  // workspace (~56.4 MiB)
  uint8_t* ws = (uint8_t*)d_ws;
  size_t off = 0;
  ushort_t* Tb  = (ushort_t*)(ws + off); off += (size_t)Ttot * D_DIM * 2;  // 8 MiB
  ushort_t* TbF = (ushort_t*)(ws + off); off += (size_t)Ttot * D_DIM * 2;  // 8 MiB
  ushort_t* TTF = (ushort_t*)(ws + off); off += (size_t)Ttot * D_DIM * 2;  // 8 MiB
  float* nrm = (float*)(ws + off); off += (size_t)Ttot * 4;
  float* sg  = (float*)(ws + off); off += (size_t)Bn * 4;
  float* sp  = (float*)(ws + off); off += (size_t)Bn * 4;
  off = (off + 255) & ~(size_t)255;
  float* Part = (float*)(ws + off); off += (size_t)4 * Bn * D_DIM * 4;     // 32 MiB
  if (ws_size < off) return;  // clean-fail signature if ws too small

  // zero sg + sp (contiguous); nrm is plain-stored by prep_all
  hipMemsetAsync(sg, 0, 2 * (size_t)Bn * sizeof(float), stream);

  prep_all<<<Ttot / 32, 256, 0, stream>>>(G, P, Tb, TbF, TTF, nrm, Bn, Ttot);
  fused_kernel<<<dim3(Bn / BI, Ttot / CHUNK), 512, 0, stream>>>(
      Tb, TbF, TTF, nrm, sg, sp, Part, Bn, Ttot);
  combine_kernel<<<(Bn * D_DIM / 4) / 256, 256, 0, stream>>>((float*)d_out, Part, sg, sp);
}

// Round 12
// 235.476 us; speedup vs baseline: 2.0053x; 2.0053x over previous
//
#include <hip/hip_runtime.h>
#include <stdint.h>

#define D_DIM 256
#define BI 64        // i-rows per block (2 blocks/CU -- the L2/VGPR sweet spot, r11 proved)
#define TJ 128       // j-tile
#define CHUNK 4096   // j per block (grid = 128 x 4 = 512 blocks = 2/CU)

typedef unsigned short ushort_t;
typedef __attribute__((ext_vector_type(8))) short bf16x8;   // 8 bf16 = 4 VGPRs
typedef __attribute__((ext_vector_type(4))) float f32x4;

__device__ __forceinline__ unsigned short f2bf(float f) {
  union { float f; unsigned u; } x; x.f = f;
  unsigned r = x.u + 0x7FFFu + ((x.u >> 16) & 1u);  // round-nearest-even
  return (unsigned short)(r >> 16);
}

__device__ __forceinline__ float fast_sqrt(float x) {
#if __has_builtin(__builtin_amdgcn_sqrtf)
  return __builtin_amdgcn_sqrtf(x);
#else
  return sqrtf(x);
#endif
}
__device__ __forceinline__ float fast_exp2(float x) {
#if __has_builtin(__builtin_amdgcn_exp2f)
  return __builtin_amdgcn_exp2f(x);
#else
  return exp2f(x);
#endif
}

// async global->LDS, 16B per lane. LDS dest = wave-uniform base + lane*16.
__device__ __forceinline__ void g2l16(const void* g, void* l) {
  __builtin_amdgcn_global_load_lds(
      (__attribute__((address_space(1))) void*)(uintptr_t)g,
      (__attribute__((address_space(3))) void*)(unsigned)(uintptr_t)l,
      16, 0, 0);
}

// ---------------- prep (fused): cast + norms + Tb + TbF + TTF in ONE pass ----------------
// r9-verified: 512 blocks x 256 threads, 32 rows/block (2 blocks/CU).
__global__ __launch_bounds__(256) void
prep_all(const float* __restrict__ G, const float* __restrict__ P,
         ushort_t* __restrict__ Tb, ushort_t* __restrict__ TbF,
         ushort_t* __restrict__ TTF, float* __restrict__ nrm,
         int Bn, int Ttot)
{
  __shared__ ushort_t Ls[32][264];   // pad 8: row stride 528B (16B-aligned)
  const int b = blockIdx.x, t = threadIdx.x;
  const int w = t >> 6, lane = t & 63;
  const int r0 = b * 32;
  const int jsteps = Ttot >> 5;

  #pragma unroll
  for (int it = 0; it < 8; it++) {
    const int rl = it * 4 + w;                // row within block (wave w owns it)
    const int r = r0 + rl;
    const float* src = (r < Bn) ? (G + (size_t)r * D_DIM)
                                : (P + (size_t)(r - Bn) * D_DIM);
    float4 v = *(const float4*)(src + lane * 4);
    ushort4 u;
    u.x = f2bf(v.x); u.y = f2bf(v.y); u.z = f2bf(v.z); u.w = f2bf(v.w);
    *(ushort4*)&Tb[(size_t)r * D_DIM + lane * 4] = u;
    *(ushort4*)&Ls[rl][lane * 4] = u;
    float s = v.x * v.x + v.y * v.y + v.z * v.z + v.w * v.w;
    #pragma unroll
    for (int o = 32; o > 0; o >>= 1) s += __shfl_down(s, o, 64);
    if (lane == 0) nrm[r] = s;                // plain store: row is wave-local
  }
  __syncthreads();

  // TbF: A-fragment layout, 2 row-groups of 16
  #pragma unroll
  for (int ii = 0; ii < 4; ii++) {
    const int flat8 = ii * 2048 + t * 8;      // [0, 8192)
    const int g4 = flat8 >> 12;               // row-group 0..1
    const int fl = flat8 & 4095;
    const int ks = fl >> 9;
    const int e = fl & 511;
    const int q = (e >> 7) & 3, m = (e >> 3) & 15;
    uint4 val = *(const uint4*)&Ls[g4 * 16 + m][ks * 32 + q * 8];
    *(uint4*)&TbF[(size_t)(b * 2 + g4) * 4096 + fl] = val;
  }

  // TTF: transposed fragment layout; this block = jstep b exactly
  #pragma unroll
  for (int ii = 0; ii < 4; ii++) {
    const int flat8 = ii * 2048 + t * 8;      // [0, 8192)
    const int dgrp = flat8 >> 9;              // 0..15
    const int e = flat8 & 511;
    const int dd = dgrp >> 2, dsub = dgrp & 3;
    const int q = (e >> 7) & 3, m = (e >> 3) & 15;
    const int col = dd * 64 + dsub * 16 + m;
    const int jrow = q * 8;
    ushort_t vals[8];
    #pragma unroll
    for (int idx = 0; idx < 8; idx++) vals[idx] = Ls[jrow + idx][col];
    *(uint4*)&TTF[((size_t)dgrp * jsteps + b) * 512 + e] = *(uint4*)vals;
  }
}

// ---------------- fused: S^T -> kv (LDS dbuf) -> O^T, 1 barrier/tile ----------------
// Round-20: r9 base (fused 159 us; r11's occupancy push catastrophically
// regressed: VGPR squeezed to 32 -> spills, af/a2 evicted from L2 -> HBM-bound)
// + ONE mechanism, isolated for the first time (r3 bundled it with the bad
// regrid): the tile barrier drains lgkmcnt ONLY. __syncthreads compiles to
// s_waitcnt vmcnt(0) lgkmcnt(0); the vmcnt(0) empties the af/a2 prefetch
// queue every tile -- the documented ~20% structural stall of this barrier
// idiom. Correctness needs only the Kbuf ds_writes visible (lgkmcnt) +
// s_barrier; the in-flight a2/af register loads carry compiler-tracked
// vmcnt waits at first use. Buffer ping-pong unchanged.
__global__ __launch_bounds__(512, 4) void
fused_kernel(const ushort_t* __restrict__ Tb, const ushort_t* __restrict__ TbF,
             const ushort_t* __restrict__ TTF, const float* __restrict__ nrm,
             float* __restrict__ sg, float* __restrict__ sp,
             float* __restrict__ Part, int Bn, int Ttot)
{
  __shared__ ushort_t Gsm[4 * 4096];      // 32 KB resident i-tile: [kq][row64][64 ^ swz]
  __shared__ ushort_t Ksm[2][64 * 128];   // 2 x 16 KB kv: [i64][128j ^ swz]

  const int t = threadIdx.x;
  const int w = t >> 6, lane = t & 63;
  const int q = lane >> 4, c = lane & 15;
  const int wj = w >> 1, wcol = w & 1;    // GEMM1 4x2 wave grid (32j x 32i each)
  const int wd = w;                       // GEMM2 8x1 wave grid (32d x 64i each)

  // XCD-chunk swizzle (bijective): XCD k <- chunk k>>1; i-blocks interleave.
  const int bid = blockIdx.y * gridDim.x + blockIdx.x;
  const int by = (bid & 7) >> 1;                  // chunk index 0..3
  const int bx = ((bid >> 3) << 1) | (bid & 1);   // i-block 0..127
  const int i0 = bx * BI;
  const int chunk0 = by * CHUNK;
  const bool gen = (chunk0 < Bn);
  const int swz = (c & 7) * 8;            // per-lane constant XOR
  const int jsteps = Ttot >> 5;
  const size_t mstride = (size_t)jsteps * 512;

  // ---- stage resident G tile (64 rows x 256 k, swizzled) ----
  const int srow = t >> 3;                               // 0..63
  const int scol = ((t & 7) * 8) ^ ((srow & 7) * 8);     // source col within 64
  {
    const ushort_t* gsrc = Tb + (size_t)(i0 + srow) * D_DIM;
    #pragma unroll
    for (int kq = 0; kq < 4; kq++)
      g2l16(gsrc + kq * 64 + scol, Gsm + kq * 4096 + t * 8);
  }

  f32x4 accO[2][4];
  #pragma unroll
  for (int m = 0; m < 2; m++)
    #pragma unroll
    for (int n = 0; n < 4; n++) accO[m][n] = (f32x4)0.f;
  float rs[2] = {0.f, 0.f};
  float ni[2];
  #pragma unroll
  for (int nt = 0; nt < 2; nt++) ni[nt] = nrm[i0 + wcol * 32 + nt * 16 + c];

  // persistent GEMM1 af prefetch registers (ks=0 of current tile)
  bf16x8 af0c, af1c;
  {
    const ushort_t* ap = TbF + ((size_t)((chunk0 >> 4) + wj * 2) * 8) * 512 + lane * 8;
    af0c = *(const bf16x8*)ap;
    af1c = *(const bf16x8*)(ap + 4096);
  }

  __syncthreads();   // Gsm ready (full drain incl. global_load_lds -- required)

  for (int jt = 0; jt < CHUNK; jt += TJ) {
    const int j0g = chunk0 + jt;
    ushort_t* Kbuf = Ksm[(jt >> 7) & 1];
    const ushort_t* afp = TbF + ((size_t)((j0g >> 4) + wj * 2) * 8) * 512 + lane * 8;

    // prefetch nrm[j] for this tile's epilogue (hidden under GEMM1)
    float4 njv[2];
    #pragma unroll
    for (int mt = 0; mt < 2; mt++)
      njv[mt] = *(const float4*)&nrm[j0g + wj * 32 + mt * 16 + q * 4];

    // ---- GEMM1: S^T[j32 x i32] per wave, K=256; af global (dbuf), bf from Gsm ----
    f32x4 acc1[2][2];
    #pragma unroll
    for (int m = 0; m < 2; m++)
      #pragma unroll
      for (int n = 0; n < 2; n++) acc1[m][n] = (f32x4)0.f;

    #pragma unroll
    for (int ks = 0; ks < 8; ks++) {
      bf16x8 afn0, afn1;
      if (ks < 7) {
        afn0 = *(const bf16x8*)(afp + (ks + 1) * 512);
        afn1 = *(const bf16x8*)(afp + 4096 + (ks + 1) * 512);
      }
      bf16x8 bf[2];
      #pragma unroll
      for (int nt = 0; nt < 2; nt++)
        bf[nt] = *(const bf16x8*)&Gsm[(ks >> 1) * 4096 + (wcol * 32 + nt * 16 + c) * 64 + ((((ks & 1) * 32) + q * 8) ^ swz)];
      #pragma unroll
      for (int nt = 0; nt < 2; nt++) {
        acc1[0][nt] = __builtin_amdgcn_mfma_f32_16x16x32_bf16(af0c, bf[nt], acc1[0][nt], 0, 0, 0);
        acc1[1][nt] = __builtin_amdgcn_mfma_f32_16x16x32_bf16(af1c, bf[nt], acc1[1][nt], 0, 0, 0);
      }
      if (ks < 7) { af0c = afn0; af1c = afn1; }
    }

    // ---- epilogue: kv = exp(-dist/20), rowsums, pack -> Kbuf ----
    #pragma unroll
    for (int mt = 0; mt < 2; mt++) {
      const int jl = wj * 32 + mt * 16 + q * 4;   // local j of reg 0
      const int jb = j0g + jl;                    // global j
      const float nj[4] = {njv[mt].x, njv[mt].y, njv[mt].z, njv[mt].w};
      #pragma unroll
      for (int nt = 0; nt < 2; nt++) {
        const int il = wcol * 32 + nt * 16 + c;
        const int ig = i0 + il;
        uint32_t pb[4];
        #pragma unroll
        for (int reg = 0; reg < 4; reg++) {
          float sq = fmaxf(ni[nt] + nj[reg] - 2.f * acc1[mt][nt][reg], 0.f);
          float dd = fast_sqrt(sq);
          float kv = fast_exp2(dd * -0.07213475204444817f);  // exp(-dd/20)
          if (gen && (jb + reg == ig)) kv = 0.f;
          rs[nt] += kv;
          union { float f; uint32_t u; } uu; uu.f = kv; pb[reg] = uu.u;
        }
        uint2 pk;  // truncating bf16 pack
        pk.x = __builtin_amdgcn_perm(pb[1], pb[0], 0x07060302u);
        pk.y = __builtin_amdgcn_perm(pb[3], pb[2], 0x07060302u);
        *(uint2*)&Kbuf[il * 128 + (jl ^ swz)] = pk;
      }
    }

    // prefetches issued before the barrier; with the lgkmcnt-only drain they
    // STAY IN FLIGHT across it and complete under GEMM2's first ds_reads.
    const ushort_t* a2p = TTF + ((size_t)(wd * 2) * jsteps + (j0g >> 5)) * 512 + lane * 8;
    bf16x8 a20 = *(const bf16x8*)a2p;
    bf16x8 a21 = *(const bf16x8*)(a2p + mstride);
    {
      const int jn = (jt + TJ < CHUNK) ? (j0g + TJ) : chunk0;
      const ushort_t* ap = TbF + ((size_t)((jn >> 4) + wj * 2) * 8) * 512 + lane * 8;
      af0c = *(const bf16x8*)ap;
      af1c = *(const bf16x8*)(ap + 4096);
    }

    // T4-lite tile barrier: Kbuf ds_writes visible (lgkmcnt), no vmcnt drain.
    asm volatile("s_waitcnt lgkmcnt(0)" ::: "memory");
    __builtin_amdgcn_s_barrier();
    __builtin_amdgcn_sched_barrier(0);

    // ---- GEMM2: O^T[d32 x i64] per wave, K=128; a2 global (dbuf), kf from Kbuf ----
    #pragma unroll
    for (int ks = 0; ks < 4; ks++) {
      bf16x8 a2n0, a2n1;
      if (ks < 3) {
        a2n0 = *(const bf16x8*)(a2p + (ks + 1) * 512);
        a2n1 = *(const bf16x8*)(a2p + mstride + (ks + 1) * 512);
      }
      bf16x8 kf[4];
      #pragma unroll
      for (int nt = 0; nt < 4; nt++)
        kf[nt] = *(const bf16x8*)&Kbuf[(nt * 16 + c) * 128 + ((ks * 32 + q * 8) ^ swz)];
      #pragma unroll
      for (int nt = 0; nt < 4; nt++) {
        accO[0][nt] = __builtin_amdgcn_mfma_f32_16x16x32_bf16(a20, kf[nt], accO[0][nt], 0, 0, 0);
        accO[1][nt] = __builtin_amdgcn_mfma_f32_16x16x32_bf16(a21, kf[nt], accO[1][nt], 0, 0, 0);
      }
      if (ks < 3) { a20 = a2n0; a21 = a2n1; }
    }
    // no barrier: next tile writes the other Ksm buffer
  }

  // rowsum partials -> sg/sp
  float* S = gen ? sg : sp;
  #pragma unroll
  for (int nt = 0; nt < 2; nt++) {
    float r = rs[nt];
    r += __shfl_xor(r, 16, 64);
    r += __shfl_xor(r, 32, 64);
    if (lane < 16) atomicAdd(&S[i0 + wcol * 32 + nt * 16 + lane], r);
  }
  // O^T partials -> Part[chunk][i][d] (f32x4, 16B aligned)
  float* Pdst = Part + (size_t)by * ((size_t)8192 * D_DIM);
  #pragma unroll
  for (int mt = 0; mt < 2; mt++)
    #pragma unroll
    for (int nt = 0; nt < 4; nt++) {
      const int d = wd * 32 + mt * 16 + q * 4;
      const int ig = i0 + nt * 16 + c;
      *(f32x4*)&Pdst[(size_t)ig * D_DIM + d] = accO[mt][nt];
    }
}

// ---------------- combine: out = sg*sum(pos parts) - sp*sum(gen parts) ----------------
__global__ __launch_bounds__(256) void
combine_kernel(float* __restrict__ out, const float* __restrict__ Part,
               const float* __restrict__ sg, const float* __restrict__ sp)
{
  const size_t idx = (size_t)blockIdx.x * 256 + threadIdx.x;   // f32x4 index
  const size_t qstride = (size_t)8192 * (D_DIM / 4);
  const int i = (int)(idx >> 6);
  const f32x4* p = (const f32x4*)Part;
  f32x4 g0 = p[idx], g1 = p[idx + qstride];
  f32x4 p0 = p[idx + 2 * qstride], p1 = p[idx + 3 * qstride];
  const float sgv = sg[i], spv = sp[i];
  f32x4 r;
  #pragma unroll
  for (int k = 0; k < 4; k++) r[k] = sgv * (p0[k] + p1[k]) - spv * (g0[k] + g1[k]);
  ((f32x4*)out)[idx] = r;
}

extern "C" void kernel_launch(void* const* d_in, const int* in_sizes, int n_in,
                              void* d_out, int out_size, void* d_ws, size_t ws_size,
                              hipStream_t stream)
{
  const float* G = (const float*)d_in[0];
  const float* P = (const float*)d_in[1];
  const int Bn = in_sizes[0] / D_DIM;   // 8192
  const int Xn = in_sizes[1] / D_DIM;   // 8192
  const int Ttot = Bn + Xn;             // 16384

  // workspace (~56.4 MiB)
  uint8_t* ws = (uint8_t*)d_ws;
  size_t off = 0;
  ushort_t* Tb  = (ushort_t*)(ws + off); off += (size_t)Ttot * D_DIM * 2;  // 8 MiB
  ushort_t* TbF = (ushort_t*)(ws + off); off += (size_t)Ttot * D_DIM * 2;  // 8 MiB
  ushort_t* TTF = (ushort_t*)(ws + off); off += (size_t)Ttot * D_DIM * 2;  // 8 MiB
  float* nrm = (float*)(ws + off); off += (size_t)Ttot * 4;
  float* sg  = (float*)(ws + off); off += (size_t)Bn * 4;
  float* sp  = (float*)(ws + off); off += (size_t)Bn * 4;
  off = (off + 255) & ~(size_t)255;
  float* Part = (float*)(ws + off); off += (size_t)4 * Bn * D_DIM * 4;     // 32 MiB
  if (ws_size < off) return;  // clean-fail signature if ws too small

  // zero sg + sp (contiguous); nrm is plain-stored by prep_all
  hipMemsetAsync(sg, 0, 2 * (size_t)Bn * sizeof(float), stream);

  prep_all<<<Ttot / 32, 256, 0, stream>>>(G, P, Tb, TbF, TTF, nrm, Bn, Ttot);
  fused_kernel<<<dim3(Bn / BI, Ttot / CHUNK), 512, 0, stream>>>(
      Tb, TbF, TTF, nrm, sg, sp, Part, Bn, Ttot);
  combine_kernel<<<(Bn * D_DIM / 4) / 256, 256, 0, stream>>>((float*)d_out, Part, sg, sp);
}

// Round 13
// 220.409 us; speedup vs baseline: 2.1424x; 1.0684x over previous
//
#include <hip/hip_runtime.h>
#include <stdint.h>

#define D_DIM 256
#define BI 64        // i-rows per block (2 blocks/CU -- L2/VGPR sweet spot; r11 proved unique)
#define TJ 128       // j-tile
#define CHUNK 4096   // j per block (grid = 128 x 4 = 512 blocks = 2/CU)

typedef unsigned short ushort_t;
typedef __attribute__((ext_vector_type(8))) short bf16x8;   // 8 bf16 = 4 VGPRs
typedef __attribute__((ext_vector_type(4))) float f32x4;

__device__ __forceinline__ unsigned short f2bf(float f) {
  union { float f; unsigned u; } x; x.f = f;
  unsigned r = x.u + 0x7FFFu + ((x.u >> 16) & 1u);  // round-nearest-even
  return (unsigned short)(r >> 16);
}

__device__ __forceinline__ float fast_sqrt(float x) {
#if __has_builtin(__builtin_amdgcn_sqrtf)
  return __builtin_amdgcn_sqrtf(x);
#else
  return sqrtf(x);
#endif
}
__device__ __forceinline__ float fast_exp2(float x) {
#if __has_builtin(__builtin_amdgcn_exp2f)
  return __builtin_amdgcn_exp2f(x);
#else
  return exp2f(x);
#endif
}

// async global->LDS, 16B per lane. LDS dest = wave-uniform base + lane*16.
__device__ __forceinline__ void g2l16(const void* g, void* l) {
  __builtin_amdgcn_global_load_lds(
      (__attribute__((address_space(1))) void*)(uintptr_t)g,
      (__attribute__((address_space(3))) void*)(unsigned)(uintptr_t)l,
      16, 0, 0);
}

// ---------------- prep (fused): cast + norms + Tb + TbF + TTF in ONE pass ----------------
// r9-verified: 512 blocks x 256 threads, 32 rows/block (2 blocks/CU, 2 waves/SIMD).
__global__ __launch_bounds__(256) void
prep_all(const float* __restrict__ G, const float* __restrict__ P,
         ushort_t* __restrict__ Tb, ushort_t* __restrict__ TbF,
         ushort_t* __restrict__ TTF, float* __restrict__ nrm,
         int Bn, int Ttot)
{
  __shared__ ushort_t Ls[32][264];   // pad 8: row stride 528B (16B-aligned)
  const int b = blockIdx.x, t = threadIdx.x;
  const int w = t >> 6, lane = t & 63;
  const int r0 = b * 32;
  const int jsteps = Ttot >> 5;

  #pragma unroll
  for (int it = 0; it < 8; it++) {
    const int rl = it * 4 + w;                // row within block (wave w owns it)
    const int r = r0 + rl;
    const float* src = (r < Bn) ? (G + (size_t)r * D_DIM)
                                : (P + (size_t)(r - Bn) * D_DIM);
    float4 v = *(const float4*)(src + lane * 4);
    ushort4 u;
    u.x = f2bf(v.x); u.y = f2bf(v.y); u.z = f2bf(v.z); u.w = f2bf(v.w);
    *(ushort4*)&Tb[(size_t)r * D_DIM + lane * 4] = u;
    *(ushort4*)&Ls[rl][lane * 4] = u;
    float s = v.x * v.x + v.y * v.y + v.z * v.z + v.w * v.w;
    #pragma unroll
    for (int o = 32; o > 0; o >>= 1) s += __shfl_down(s, o, 64);
    if (lane == 0) nrm[r] = s;                // plain store: row is wave-local
  }
  __syncthreads();

  // TbF: A-fragment layout, 2 row-groups of 16
  #pragma unroll
  for (int ii = 0; ii < 4; ii++) {
    const int flat8 = ii * 2048 + t * 8;      // [0, 8192)
    const int g4 = flat8 >> 12;               // row-group 0..1
    const int fl = flat8 & 4095;
    const int ks = fl >> 9;
    const int e = fl & 511;
    const int q = (e >> 7) & 3, m = (e >> 3) & 15;
    uint4 val = *(const uint4*)&Ls[g4 * 16 + m][ks * 32 + q * 8];
    *(uint4*)&TbF[(size_t)(b * 2 + g4) * 4096 + fl] = val;
  }

  // TTF: transposed fragment layout; this block = jstep b exactly
  #pragma unroll
  for (int ii = 0; ii < 4; ii++) {
    const int flat8 = ii * 2048 + t * 8;      // [0, 8192)
    const int dgrp = flat8 >> 9;              // 0..15
    const int e = flat8 & 511;
    const int dd = dgrp >> 2, dsub = dgrp & 3;
    const int q = (e >> 7) & 3, m = (e >> 3) & 15;
    const int col = dd * 64 + dsub * 16 + m;
    const int jrow = q * 8;
    ushort_t vals[8];
    #pragma unroll
    for (int idx = 0; idx < 8; idx++) vals[idx] = Ls[jrow + idx][col];
    *(uint4*)&TTF[((size_t)dgrp * jsteps + b) * 512 + e] = *(uint4*)vals;
  }
}

// ---------------- fused: S^T -> kv (LDS dbuf) -> O^T, 1 barrier/tile ----------------
// FROZEN r4/r9 structure (fused ~159 us, the verified optimum of this shape).
// Attribution ledger: +XCD-chunk swizzle & pre-barrier prefetch (r4, kept);
// interleave (r1), regrids (r3/r6), LDS reg-dbuf (r5), 32-waves/CU (r11),
// lgkmcnt-only barrier (r12) all regressed or neutral; cross-dispatch fusion
// (r8 fence, r10 cooperative) fails in this harness.
__global__ __launch_bounds__(512, 4) void
fused_kernel(const ushort_t* __restrict__ Tb, const ushort_t* __restrict__ TbF,
             const ushort_t* __restrict__ TTF, const float* __restrict__ nrm,
             float* __restrict__ sg, float* __restrict__ sp,
             float* __restrict__ Part, int Bn, int Ttot)
{
  __shared__ ushort_t Gsm[4 * 4096];      // 32 KB resident i-tile: [kq][row64][64 ^ swz]
  __shared__ ushort_t Ksm[2][64 * 128];   // 2 x 16 KB kv: [i64][128j ^ swz]

  const int t = threadIdx.x;
  const int w = t >> 6, lane = t & 63;
  const int q = lane >> 4, c = lane & 15;
  const int wj = w >> 1, wcol = w & 1;    // GEMM1 4x2 wave grid (32j x 32i each)
  const int wd = w;                       // GEMM2 8x1 wave grid (32d x 64i each)

  // XCD-chunk swizzle (bijective): XCD k <- chunk k>>1; i-blocks interleave.
  const int bid = blockIdx.y * gridDim.x + blockIdx.x;
  const int by = (bid & 7) >> 1;                  // chunk index 0..3
  const int bx = ((bid >> 3) << 1) | (bid & 1);   // i-block 0..127
  const int i0 = bx * BI;
  const int chunk0 = by * CHUNK;
  const bool gen = (chunk0 < Bn);
  const int swz = (c & 7) * 8;            // per-lane constant XOR
  const int jsteps = Ttot >> 5;
  const size_t mstride = (size_t)jsteps * 512;

  // ---- stage resident G tile (64 rows x 256 k, swizzled) ----
  const int srow = t >> 3;                               // 0..63
  const int scol = ((t & 7) * 8) ^ ((srow & 7) * 8);     // source col within 64
  {
    const ushort_t* gsrc = Tb + (size_t)(i0 + srow) * D_DIM;
    #pragma unroll
    for (int kq = 0; kq < 4; kq++)
      g2l16(gsrc + kq * 64 + scol, Gsm + kq * 4096 + t * 8);
  }

  f32x4 accO[2][4];
  #pragma unroll
  for (int m = 0; m < 2; m++)
    #pragma unroll
    for (int n = 0; n < 4; n++) accO[m][n] = (f32x4)0.f;
  float rs[2] = {0.f, 0.f};
  float ni[2];
  #pragma unroll
  for (int nt = 0; nt < 2; nt++) ni[nt] = nrm[i0 + wcol * 32 + nt * 16 + c];

  // persistent GEMM1 af prefetch registers (ks=0 of current tile)
  bf16x8 af0c, af1c;
  {
    const ushort_t* ap = TbF + ((size_t)((chunk0 >> 4) + wj * 2) * 8) * 512 + lane * 8;
    af0c = *(const bf16x8*)ap;
    af1c = *(const bf16x8*)(ap + 4096);
  }

  __syncthreads();   // Gsm ready

  for (int jt = 0; jt < CHUNK; jt += TJ) {
    const int j0g = chunk0 + jt;
    ushort_t* Kbuf = Ksm[(jt >> 7) & 1];
    const ushort_t* afp = TbF + ((size_t)((j0g >> 4) + wj * 2) * 8) * 512 + lane * 8;

    // prefetch nrm[j] for this tile's epilogue (hidden under GEMM1)
    float4 njv[2];
    #pragma unroll
    for (int mt = 0; mt < 2; mt++)
      njv[mt] = *(const float4*)&nrm[j0g + wj * 32 + mt * 16 + q * 4];

    // ---- GEMM1: S^T[j32 x i32] per wave, K=256; af global (dbuf), bf from Gsm ----
    f32x4 acc1[2][2];
    #pragma unroll
    for (int m = 0; m < 2; m++)
      #pragma unroll
      for (int n = 0; n < 2; n++) acc1[m][n] = (f32x4)0.f;

    #pragma unroll
    for (int ks = 0; ks < 8; ks++) {
      bf16x8 afn0, afn1;
      if (ks < 7) {
        afn0 = *(const bf16x8*)(afp + (ks + 1) * 512);
        afn1 = *(const bf16x8*)(afp + 4096 + (ks + 1) * 512);
      }
      bf16x8 bf[2];
      #pragma unroll
      for (int nt = 0; nt < 2; nt++)
        bf[nt] = *(const bf16x8*)&Gsm[(ks >> 1) * 4096 + (wcol * 32 + nt * 16 + c) * 64 + ((((ks & 1) * 32) + q * 8) ^ swz)];
      #pragma unroll
      for (int nt = 0; nt < 2; nt++) {
        acc1[0][nt] = __builtin_amdgcn_mfma_f32_16x16x32_bf16(af0c, bf[nt], acc1[0][nt], 0, 0, 0);
        acc1[1][nt] = __builtin_amdgcn_mfma_f32_16x16x32_bf16(af1c, bf[nt], acc1[1][nt], 0, 0, 0);
      }
      if (ks < 7) { af0c = afn0; af1c = afn1; }
    }

    // ---- epilogue: kv = exp(-dist/20), rowsums, pack -> Kbuf ----
    #pragma unroll
    for (int mt = 0; mt < 2; mt++) {
      const int jl = wj * 32 + mt * 16 + q * 4;   // local j of reg 0
      const int jb = j0g + jl;                    // global j
      const float nj[4] = {njv[mt].x, njv[mt].y, njv[mt].z, njv[mt].w};
      #pragma unroll
      for (int nt = 0; nt < 2; nt++) {
        const int il = wcol * 32 + nt * 16 + c;
        const int ig = i0 + il;
        uint32_t pb[4];
        #pragma unroll
        for (int reg = 0; reg < 4; reg++) {
          float sq = fmaxf(ni[nt] + nj[reg] - 2.f * acc1[mt][nt][reg], 0.f);
          float dd = fast_sqrt(sq);
          float kv = fast_exp2(dd * -0.07213475204444817f);  // exp(-dd/20)
          if (gen && (jb + reg == ig)) kv = 0.f;
          rs[nt] += kv;
          union { float f; uint32_t u; } uu; uu.f = kv; pb[reg] = uu.u;
        }
        uint2 pk;  // truncating bf16 pack
        pk.x = __builtin_amdgcn_perm(pb[1], pb[0], 0x07060302u);
        pk.y = __builtin_amdgcn_perm(pb[3], pb[2], 0x07060302u);
        *(uint2*)&Kbuf[il * 128 + (jl ^ swz)] = pk;
      }
    }

    // pre-barrier prefetches: completed by the barrier's vmcnt(0) drain,
    // issued under the epilogue VALU work above.
    const ushort_t* a2p = TTF + ((size_t)(wd * 2) * jsteps + (j0g >> 5)) * 512 + lane * 8;
    bf16x8 a20 = *(const bf16x8*)a2p;
    bf16x8 a21 = *(const bf16x8*)(a2p + mstride);
    {
      const int jn = (jt + TJ < CHUNK) ? (j0g + TJ) : chunk0;
      const ushort_t* ap = TbF + ((size_t)((jn >> 4) + wj * 2) * 8) * 512 + lane * 8;
      af0c = *(const bf16x8*)ap;
      af1c = *(const bf16x8*)(ap + 4096);
    }

    __syncthreads();   // Kbuf ready (sole barrier; dbuf covers cross-tile reuse)

    // ---- GEMM2: O^T[d32 x i64] per wave, K=128; a2 global (dbuf), kf from Kbuf ----
    #pragma unroll
    for (int ks = 0; ks < 4; ks++) {
      bf16x8 a2n0, a2n1;
      if (ks < 3) {
        a2n0 = *(const bf16x8*)(a2p + (ks + 1) * 512);
        a2n1 = *(const bf16x8*)(a2p + mstride + (ks + 1) * 512);
      }
      bf16x8 kf[4];
      #pragma unroll
      for (int nt = 0; nt < 4; nt++)
        kf[nt] = *(const bf16x8*)&Kbuf[(nt * 16 + c) * 128 + ((ks * 32 + q * 8) ^ swz)];
      #pragma unroll
      for (int nt = 0; nt < 4; nt++) {
        accO[0][nt] = __builtin_amdgcn_mfma_f32_16x16x32_bf16(a20, kf[nt], accO[0][nt], 0, 0, 0);
        accO[1][nt] = __builtin_amdgcn_mfma_f32_16x16x32_bf16(a21, kf[nt], accO[1][nt], 0, 0, 0);
      }
      if (ks < 3) { a20 = a2n0; a21 = a2n1; }
    }
    // no barrier: next tile writes the other Ksm buffer
  }

  // rowsum partials -> sg/sp
  float* S = gen ? sg : sp;
  #pragma unroll
  for (int nt = 0; nt < 2; nt++) {
    float r = rs[nt];
    r += __shfl_xor(r, 16, 64);
    r += __shfl_xor(r, 32, 64);
    if (lane < 16) atomicAdd(&S[i0 + wcol * 32 + nt * 16 + lane], r);
  }
  // O^T partials -> Part[chunk][i][d] (f32x4, 16B aligned)
  float* Pdst = Part + (size_t)by * ((size_t)8192 * D_DIM);
  #pragma unroll
  for (int mt = 0; mt < 2; mt++)
    #pragma unroll
    for (int nt = 0; nt < 4; nt++) {
      const int d = wd * 32 + mt * 16 + q * 4;
      const int ig = i0 + nt * 16 + c;
      *(f32x4*)&Pdst[(size_t)ig * D_DIM + d] = accO[mt][nt];
    }
}

// ---------------- combine: out = sg*sum(pos parts) - sp*sum(gen parts) ----------------
__global__ __launch_bounds__(256) void
combine_kernel(float* __restrict__ out, const float* __restrict__ Part,
               const float* __restrict__ sg, const float* __restrict__ sp)
{
  const size_t idx = (size_t)blockIdx.x * 256 + threadIdx.x;   // f32x4 index
  const size_t qstride = (size_t)8192 * (D_DIM / 4);
  const int i = (int)(idx >> 6);
  const f32x4* p = (const f32x4*)Part;
  f32x4 g0 = p[idx], g1 = p[idx + qstride];
  f32x4 p0 = p[idx + 2 * qstride], p1 = p[idx + 3 * qstride];
  const float sgv = sg[i], spv = sp[i];
  f32x4 r;
  #pragma unroll
  for (int k = 0; k < 4; k++) r[k] = sgv * (p0[k] + p1[k]) - spv * (g0[k] + g1[k]);
  ((f32x4*)out)[idx] = r;
}

extern "C" void kernel_launch(void* const* d_in, const int* in_sizes, int n_in,
                              void* d_out, int out_size, void* d_ws, size_t ws_size,
                              hipStream_t stream)
{
  const float* G = (const float*)d_in[0];
  const float* P = (const float*)d_in[1];
  const int Bn = in_sizes[0] / D_DIM;   // 8192
  const int Xn = in_sizes[1] / D_DIM;   // 8192
  const int Ttot = Bn + Xn;             // 16384

  // workspace (~56.4 MiB)
  uint8_t* ws = (uint8_t*)d_ws;
  size_t off = 0;
  ushort_t* Tb  = (ushort_t*)(ws + off); off += (size_t)Ttot * D_DIM * 2;  // 8 MiB
  ushort_t* TbF = (ushort_t*)(ws + off); off += (size_t)Ttot * D_DIM * 2;  // 8 MiB
  ushort_t* TTF = (ushort_t*)(ws + off); off += (size_t)Ttot * D_DIM * 2;  // 8 MiB
  float* nrm = (float*)(ws + off); off += (size_t)Ttot * 4;
  float* sg  = (float*)(ws + off); off += (size_t)Bn * 4;
  float* sp  = (float*)(ws + off); off += (size_t)Bn * 4;
  off = (off + 255) & ~(size_t)255;
  float* Part = (float*)(ws + off); off += (size_t)4 * Bn * D_DIM * 4;     // 32 MiB
  if (ws_size < off) return;  // clean-fail signature if ws too small

  // zero sg + sp (contiguous); nrm is plain-stored by prep_all
  hipMemsetAsync(sg, 0, 2 * (size_t)Bn * sizeof(float), stream);

  prep_all<<<Ttot / 32, 256, 0, stream>>>(G, P, Tb, TbF, TTF, nrm, Bn, Ttot);
  fused_kernel<<<dim3(Bn / BI, Ttot / CHUNK), 512, 0, stream>>>(
      Tb, TbF, TTF, nrm, sg, sp, Part, Bn, Ttot);
  combine_kernel<<<(Bn * D_DIM / 4) / 256, 256, 0, stream>>>((float*)d_out, Part, sg, sp);
}